// Round 1
// baseline (43.174 us; speedup 1.0000x reference)
//
#include <hip/hip_runtime.h>

// 3D inverse Haar DWT, N=256 (input octants 128^3, 16 channels = 8 subbands x 2 ch).
// out[(2i+ap),(2j+bp),(2k+cp),ch] = r^3 * sum_{a,b,c} sgn(a,ap) sgn(b,bp) sgn(c,cp)
//                                     * x[i,j,k,(4a+2b+c)*2+ch]
// sgn(bit,par) = bit==0 ? +1 : (par ? +1 : -1)   (Haar synthesis from S = A^T)

#define NH 128          // N/2
#define NFULL 256

__global__ __launch_bounds__(256) void idwt3_haar_kernel(
    const float* __restrict__ x,
    const float* __restrict__ S,
    float* __restrict__ out)
{
    const int t = blockIdx.x * blockDim.x + threadIdx.x;
    if (t >= NH * NH * NH) return;

    const int k = t & (NH - 1);
    const int j = (t >> 7) & (NH - 1);
    const int i = t >> 14;

    // 16 contiguous floats at this site: [subband 0..7][ch 0..1]
    const float4* __restrict__ xp = reinterpret_cast<const float4*>(x) + (size_t)t * 4;
    float in[16];
    *reinterpret_cast<float4*>(&in[0])  = xp[0];
    *reinterpret_cast<float4*>(&in[4])  = xp[1];
    *reinterpret_cast<float4*>(&in[8])  = xp[2];
    *reinterpret_cast<float4*>(&in[12]) = xp[3];

    const float r  = S[0];        // = 1/sqrt(2), read from the actual S matrix
    const float s3 = r * r * r;

    // Stage 1: axis-3 butterfly. t1[a][b][c_par][ch]
    float t1[2][2][2][2];
#pragma unroll
    for (int a = 0; a < 2; ++a)
#pragma unroll
        for (int b = 0; b < 2; ++b)
#pragma unroll
            for (int ch = 0; ch < 2; ++ch) {
                float lo = in[(4 * a + 2 * b + 0) * 2 + ch];
                float hi = in[(4 * a + 2 * b + 1) * 2 + ch];
                t1[a][b][0][ch] = lo - hi;
                t1[a][b][1][ch] = lo + hi;
            }

    // Stage 2: axis-2 butterfly. t2[a][b_par][c_par][ch]
    float t2[2][2][2][2];
#pragma unroll
    for (int a = 0; a < 2; ++a)
#pragma unroll
        for (int cp = 0; cp < 2; ++cp)
#pragma unroll
            for (int ch = 0; ch < 2; ++ch) {
                float lo = t1[a][0][cp][ch];
                float hi = t1[a][1][cp][ch];
                t2[a][0][cp][ch] = lo - hi;
                t2[a][1][cp][ch] = lo + hi;
            }

    // Stage 3: axis-1 butterfly + scale. t3[a_par][b_par][c_par][ch]
    float t3[2][2][2][2];
#pragma unroll
    for (int bp = 0; bp < 2; ++bp)
#pragma unroll
        for (int cp = 0; cp < 2; ++cp)
#pragma unroll
            for (int ch = 0; ch < 2; ++ch) {
                float lo = t2[0][bp][cp][ch];
                float hi = t2[1][bp][cp][ch];
                t3[0][bp][cp][ch] = s3 * (lo - hi);
                t3[1][bp][cp][ch] = s3 * (lo + hi);
            }

    // Write 2x2x2 output block: per (ap,bp) one float4 = {cp0ch0, cp0ch1, cp1ch0, cp1ch1}
    float4* __restrict__ op = reinterpret_cast<float4*>(out);
#pragma unroll
    for (int ap = 0; ap < 2; ++ap)
#pragma unroll
        for (int bp = 0; bp < 2; ++bp) {
            float4 w;
            w.x = t3[ap][bp][0][0];
            w.y = t3[ap][bp][0][1];
            w.z = t3[ap][bp][1][0];
            w.w = t3[ap][bp][1][1];
            // float element base = ((2i+ap)*256 + (2j+bp))*256*2 + (2k)*2 ; /4 for float4
            size_t f4idx = ((size_t)(2 * i + ap) * NFULL + (size_t)(2 * j + bp)) * (NFULL / 2)
                         + (size_t)k;
            op[f4idx] = w;
        }
}

extern "C" void kernel_launch(void* const* d_in, const int* in_sizes, int n_in,
                              void* d_out, int out_size, void* d_ws, size_t ws_size,
                              hipStream_t stream)
{
    const float* x = (const float*)d_in[0];   // [1,128,128,128,16] f32
    const float* S = (const float*)d_in[1];   // [256,256] f32 (Haar synthesis)
    float* out = (float*)d_out;               // [1,256,256,256,2] f32

    const int total = NH * NH * NH;           // one thread per input site
    const int block = 256;
    const int grid = (total + block - 1) / block;
    idwt3_haar_kernel<<<grid, block, 0, stream>>>(x, S, out);
}